// Round 3
// baseline (616.448 us; speedup 1.0000x reference)
//
#include <hip/hip_runtime.h>
#include <hip/hip_bf16.h>
#include <cmath>

#define BATCH 32
#define CIN   512
#define BR    256
#define LEN   4096
#define TL    32        // output positions per block (16-aligned -> aligned stores)
#define ROWS  34        // TL + 2 halo rows (l0-1 .. l0+32)
#define RS    264       // LDS row stride (bf16 elements), 256 + 8 pad
#define NBLK  128       // LEN / TL exactly

typedef __attribute__((ext_vector_type(8))) short bf16x8;
typedef __attribute__((ext_vector_type(4))) float f32x4;

#define MFMA_BF16(a,b,c) __builtin_amdgcn_mfma_f32_16x16x32_bf16((a),(b),(c),0,0,0)

__device__ __forceinline__ float bf2f(unsigned short h){
  union { unsigned int u; float f; } c; c.u = ((unsigned int)h) << 16; return c.f;
}
// HW RNE f32->bf16 (v_cvt_pk_bf16_f32 when paired by compiler) — same rounding as manual RNE.
__device__ __forceinline__ unsigned short cvt1(float f){
  union { __hip_bfloat16 h; unsigned short u; } c; c.h = __float2bfloat16(f); return c.u;
}
__device__ __forceinline__ unsigned int pack2(float a, float b){
  return (unsigned int)cvt1(a) | ((unsigned int)cvt1(b) << 16);
}
// mish(x) = x*u/(u+2), u = p*(p+2), p = e^x; fast rcp (1 ulp) instead of full divide.
__device__ __forceinline__ float mish_f(float v){
  float p = __expf(fminf(v, 40.0f));
  float u = p * (p + 2.0f);
  return v * u * __builtin_amdgcn_rcpf(u + 2.0f);
}
__device__ __forceinline__ void unpack8(const uint4 v, float* f){
  f[0] = bf2f((unsigned short)(v.x & 0xffffu)); f[1] = bf2f((unsigned short)(v.x >> 16));
  f[2] = bf2f((unsigned short)(v.y & 0xffffu)); f[3] = bf2f((unsigned short)(v.y >> 16));
  f[4] = bf2f((unsigned short)(v.z & 0xffffu)); f[5] = bf2f((unsigned short)(v.z >> 16));
  f[6] = bf2f((unsigned short)(v.w & 0xffffu)); f[7] = bf2f((unsigned short)(v.w >> 16));
}

// ---------------- prep: fold BN, fold a2 into w2 taps, W1/W3 -> bf16 (into d_ws) --------------
// folds layout (floats): [0]=a1 [256]=b1 [512]=unused [768]=b2 [1024]=a3 [1280]=b3
//                        [1536]=a2*w2 tap0 [1792]=a2*tap1 [2048]=a2*tap2
__global__ void prep_kernel(const float* __restrict__ w1, const float* __restrict__ w2,
                            const float* __restrict__ w3,
                            const float* __restrict__ b1w, const float* __restrict__ b1b,
                            const float* __restrict__ b1rm, const float* __restrict__ b1rv,
                            const float* __restrict__ b2w, const float* __restrict__ b2b,
                            const float* __restrict__ b2rm, const float* __restrict__ b2rv,
                            const float* __restrict__ b3w, const float* __restrict__ b3b,
                            const float* __restrict__ b3rm, const float* __restrict__ b3rv,
                            unsigned short* __restrict__ w1bf, unsigned short* __restrict__ w3bf,
                            float* __restrict__ folds)
{
  const int g = blockIdx.x * 256 + threadIdx.x;   // 256 blocks x 256 thr = 65536 = 256*256
  w1bf[g] = cvt1(w1[g]);
  w3bf[g] = cvt1(w3[g]);
  if (blockIdx.x == 0) {
    const int c = threadIdx.x;
    float a1 = b1w[c] / sqrtf(b1rv[c] + 1e-5f);
    folds[c]        = a1; folds[256 + c]  = b1b[c] - b1rm[c] * a1;
    float a2 = b2w[c] / sqrtf(b2rv[c] + 1e-5f);
    folds[768 + c]  = b2b[c] - b2rm[c] * a2;
    float a3 = b3w[c] / sqrtf(b3rv[c] + 1e-5f);
    folds[1024 + c] = a3; folds[1280 + c] = b3b[c] - b3rm[c] * a3;
    folds[1536 + c] = a2 * w2[c * 3 + 0];          // a2 folded into taps -> 3-FMA conv
    folds[1792 + c] = a2 * w2[c * 3 + 1];
    folds[2048 + c] = a2 * w2[c * 3 + 2];
  }
}

// ---------------- main fused kernel (x2 path + embedded x1 bit-copy) ----------------
// LDS 36 KB -> 4 blocks/CU (16 waves/CU). x1 copy: 2 batches of 4 float4; loads issued at
// phase start (after a barrier), stores issued after the NEXT barrier -> a full compute phase
// hides each latency and no barrier-drain ever waits on an unarrived load.
__global__ __launch_bounds__(256, 4)
void fused_main(const float* __restrict__ xg,
                const int*   __restrict__ maskg,
                const unsigned short* __restrict__ w1bf,
                const unsigned short* __restrict__ w3bf,
                const float* __restrict__ fa1, const float* __restrict__ fb1,
                const float* __restrict__ fb2,
                const float* __restrict__ fa3, const float* __restrict__ fb3,
                const float* __restrict__ w2p,
                float*       __restrict__ outg)
{
  __shared__ __align__(16) unsigned short ls_x2[ROWS * RS];   // x2 tile [row][ch]; reused as t2
  __shared__ __align__(16) unsigned short ls_t1[ROWS * RS];   // t1 tile [row][ch]
  __shared__ int ls_mk[48];                                   // mask window l0-1..l0+32, 0-padded

  const int tid = threadIdx.x;
  const int bx  = blockIdx.x;          // l-tile 0..127
  const int b   = blockIdx.y;          // batch
  const int l0  = bx * TL;             // 16-aligned

  // x1 copy indexing: 8,388,608 float4 chunks over 4096 blocks x 256 thr x 8
  const size_t xstr = (size_t)NBLK * BATCH * 256;             // 1,048,576
  const size_t i0   = ((size_t)b * NBLK + bx) * 256 + tid;

  // ---------- issue x1 batch-0 loads (stores happen after next barrier) ----------
  float4 x1v[4];
  #pragma unroll
  for (int k = 0; k < 4; ++k) {
    const size_t idx = i0 + (size_t)k * xstr;
    const int l  = (int)((idx & 1023) * 4);
    const int c  = (int)((idx >> 10) & 255);
    const int bb = (int)(idx >> 18);
    x1v[k] = *(const float4*)(xg + (size_t)(bb * CIN + c) * LEN + l);
  }

  // ---------- issue staging loads: thread owns channel row c=tid, 10 pos-quads ----------
  float4 stg[10];
  {
    const float* xrow = xg + (size_t)(b * CIN + BR + tid) * LEN;
    #pragma unroll
    for (int j = 0; j < 10; ++j) {
      const int lgc = min(max(l0 - 4 + 4 * j, 0), LEN - 4);
      stg[j] = *(const float4*)(xrow + lgc);
    }
  }

  // ---------- mask window -> LDS (entries beyond ROWS or OOB l are 0) ----------
  if (tid < 48) {
    const int l = l0 - 1 + tid;
    ls_mk[tid] = (tid < 48 && tid < ROWS && l >= 0 && l < LEN) ? maskg[b * LEN + l] : 0;
  }

  // ---------- zero-init only on edge blocks (rows never written stay 0) ----------
  if (bx == 0 || bx == NBLK - 1) {
    uint4* z = (uint4*)ls_x2;
    const uint4 zz = make_uint4(0, 0, 0, 0);
    for (int i = tid; i < (ROWS * RS) / 8; i += 256) z[i] = zz;
    __syncthreads();                   // block-uniform condition -> legal
  }

  // ---------- convert + store staged x2 -> LDS bf16 [row][ch] ----------
  // Per-instruction: 64 lanes write consecutive 2B (same row p, ch=lane) -> conflict-free.
  // p is wave-uniform; interior blocks cover p=0..33 exactly; clamps duplicate identical vals.
  #pragma unroll
  for (int j = 0; j < 10; ++j) {
    const int lgc = min(max(l0 - 4 + 4 * j, 0), LEN - 4);
    const float* sp = (const float*)&stg[j];
    #pragma unroll
    for (int jj = 0; jj < 4; ++jj) {
      const int p = (lgc + jj) - (l0 - 1);
      if (p >= 0 && p < ROWS) ls_x2[p * RS + tid] = cvt1(sp[jj]);
    }
  }
  __syncthreads();

  const int lane = tid & 63;
  const int wid  = tid >> 6;     // wave 0..3
  const int xl   = lane & 15;    // MFMA m/n index
  const int qd   = lane >> 4;    // MFMA quad

  float4 x1w[4];

  // ---------- GEMM1 phase: x1 b0 stores + b1 loads issued first, then compute ----------
  {
    #pragma unroll
    for (int k = 0; k < 4; ++k) {
      const size_t idx = i0 + (size_t)k * xstr;
      const int l  = (int)((idx & 1023) * 4);
      const int c  = (int)((idx >> 10) & 255);
      const int bb = (int)(idx >> 18);
      *(float4*)(outg + (size_t)(bb * CIN + 2 * c + 1) * LEN + l) = x1v[k];
    }
    #pragma unroll
    for (int k = 4; k < 8; ++k) {
      const size_t idx = i0 + (size_t)k * xstr;
      const int l  = (int)((idx & 1023) * 4);
      const int c  = (int)((idx >> 10) & 255);
      const int bb = (int)(idx >> 18);
      x1w[k - 4] = *(const float4*)(xg + (size_t)(bb * CIN + c) * LEN + l);
    }

    // GEMM1: t1 = mask*bn1(mish(W1 @ x2)) -> ls_t1 [row][ch]
    // 3 j-groups: rows 0..15, 16..31, {32,33} (third group 2/16 useful, covers conv halo).
    int mk1[3];
    #pragma unroll
    for (int j = 0; j < 3; ++j)
      mk1[j] = ls_mk[16 * j + xl];          // rows >= ROWS read padded zeros
    #pragma unroll
    for (int mi = 0; mi < 4; ++mi) {
      const int ob = (wid * 4 + mi) * 16;
      bf16x8 af[8];                          // W1 bf16 fragments, direct 16B loads (L2-hot)
      #pragma unroll
      for (int k = 0; k < 8; ++k)
        af[k] = *(const bf16x8*)&w1bf[(size_t)(ob + xl) * 256 + k * 32 + qd * 8];
      const f32x4 av = *(const f32x4*)&fa1[ob + 4 * qd];
      const f32x4 bv = *(const f32x4*)&fb1[ob + 4 * qd];
      #pragma unroll
      for (int j = 0; j < 3; ++j) {
        const int p  = 16 * j + xl;
        const int rp = min(p, ROWS - 1);     // j=2 lanes xl>=2 read duplicate row (discarded)
        bf16x8 bfr[8];
        #pragma unroll
        for (int k = 0; k < 8; ++k)
          bfr[k] = *(const bf16x8*)&ls_x2[rp * RS + k * 32 + qd * 8];
        f32x4 acc = {0.f, 0.f, 0.f, 0.f};
        #pragma unroll
        for (int k = 0; k < 8; ++k) acc = MFMA_BF16(af[k], bfr[k], acc);
        float y[4];
        #pragma unroll
        for (int r = 0; r < 4; ++r) {
          float v = mish_f(acc[r]);
          v = av[r] * v + bv[r];
          if (!mk1[j]) v = 0.0f;
          y[r] = v;
        }
        if (p < ROWS) {
          *(uint2*)&ls_t1[p * RS + ob + 4 * qd] =
              make_uint2(pack2(y[0], y[1]), pack2(y[2], y[3]));
        }
      }
    }
  }
  __syncthreads();

  // ---------- conv phase: x1 b1 stores first, then depthwise conv3+bn2+mask -> ls_x2 ----------
  {
    #pragma unroll
    for (int k = 0; k < 4; ++k) {
      const size_t idx = i0 + (size_t)(k + 4) * xstr;
      const int l  = (int)((idx & 1023) * 4);
      const int c  = (int)((idx >> 10) & 255);
      const int bb = (int)(idx >> 18);
      *(float4*)(outg + (size_t)(bb * CIN + 2 * c + 1) * LEN + l) = x1w[k];
    }

    const int c0    = (tid & 31) * 8;
    const int qbase = tid >> 5;
    const f32x4 k0a = *(const f32x4*)&w2p[      c0], k0b = *(const f32x4*)&w2p[      c0 + 4];
    const f32x4 k1a = *(const f32x4*)&w2p[256 + c0], k1b = *(const f32x4*)&w2p[256 + c0 + 4];
    const f32x4 k2a = *(const f32x4*)&w2p[512 + c0], k2b = *(const f32x4*)&w2p[512 + c0 + 4];
    const f32x4 b2a = *(const f32x4*)&fb2[c0],       b2b = *(const f32x4*)&fb2[c0 + 4];
    #pragma unroll
    for (int it = 0; it < 4; ++it) {
      const int qo = qbase + 8 * it;      // 0..31, each (qo,c0) exactly once
      const int mk = ls_mk[1 + qo];
      const uint4 ra = *(const uint4*)&ls_t1[(qo    ) * RS + c0];
      const uint4 rb = *(const uint4*)&ls_t1[(qo + 1) * RS + c0];
      const uint4 rc = *(const uint4*)&ls_t1[(qo + 2) * RS + c0];
      float ta[8], tb[8], tc[8];
      unpack8(ra, ta); unpack8(rb, tb); unpack8(rc, tc);
      float y[8];
      #pragma unroll
      for (int i = 0; i < 4; ++i) {
        y[i]     = fmaf(k0a[i], ta[i],     fmaf(k1a[i], tb[i],     fmaf(k2a[i], tc[i],     b2a[i])));
        y[4 + i] = fmaf(k0b[i], ta[4 + i], fmaf(k1b[i], tb[4 + i], fmaf(k2b[i], tc[4 + i], b2b[i])));
      }
      #pragma unroll
      for (int i = 0; i < 8; ++i) if (!mk) y[i] = 0.0f;
      uint4 wv;
      wv.x = pack2(y[0], y[1]);
      wv.y = pack2(y[2], y[3]);
      wv.z = pack2(y[4], y[5]);
      wv.w = pack2(y[6], y[7]);
      *(uint4*)&ls_x2[qo * RS + c0] = wv;
    }
  }
  __syncthreads();

  // ---------- GEMM2 (operand-swapped): D[m=pos][n=ch] = t2 @ W3^T ----------
  // Each lane owns channel ob+xl at 4 consecutive l (l0+16j+4qd+r) -> aligned float4 store.
  {
    int mks[2][4];
    #pragma unroll
    for (int j = 0; j < 2; ++j)
      #pragma unroll
      for (int r = 0; r < 4; ++r)
        mks[j][r] = ls_mk[1 + 16 * j + 4 * qd + r];
    #pragma unroll
    for (int mi = 0; mi < 4; ++mi) {
      const int ob = (wid * 4 + mi) * 16;
      bf16x8 af[8];                       // W3 bf16 fragments (B operand: n=xl, k-slice qd)
      #pragma unroll
      for (int k = 0; k < 8; ++k)
        af[k] = *(const bf16x8*)&w3bf[(size_t)(ob + xl) * 256 + k * 32 + qd * 8];
      const float a3v = fa3[ob + xl];
      const float b3v = fb3[ob + xl];
      #pragma unroll
      for (int j = 0; j < 2; ++j) {
        bf16x8 ta2[8];                    // t2 fragments (A operand: m=xl row, k-slice qd)
        #pragma unroll
        for (int k = 0; k < 8; ++k)
          ta2[k] = *(const bf16x8*)&ls_x2[(16 * j + xl) * RS + k * 32 + qd * 8];
        f32x4 acc = {0.f, 0.f, 0.f, 0.f};
        #pragma unroll
        for (int k = 0; k < 8; ++k) acc = MFMA_BF16(ta2[k], af[k], acc);
        float4 ov;
        float* op = &ov.x;
        #pragma unroll
        for (int r = 0; r < 4; ++r) {
          float v = mish_f(acc[r]);
          v = a3v * v + b3v;
          if (!mks[j][r]) v = 0.0f;
          op[r] = v;
        }
        *(float4*)&outg[(size_t)(b * CIN + 2 * (ob + xl)) * LEN + l0 + 16 * j + 4 * qd] = ov;
      }
    }
  }
}

extern "C" void kernel_launch(void* const* d_in, const int* in_sizes, int n_in,
                              void* d_out, int out_size, void* d_ws, size_t ws_size,
                              hipStream_t stream) {
  (void)in_sizes; (void)n_in; (void)out_size; (void)ws_size;
  const float* xg    = (const float*)d_in[0];
  const int*   maskg = (const int*)d_in[1];
  const float* w1    = (const float*)d_in[2];
  const float* w2    = (const float*)d_in[3];
  const float* w3    = (const float*)d_in[4];
  const float* b1w   = (const float*)d_in[5];
  const float* b1b   = (const float*)d_in[6];
  const float* b1rm  = (const float*)d_in[7];
  const float* b1rv  = (const float*)d_in[8];
  const float* b2w   = (const float*)d_in[9];
  const float* b2b   = (const float*)d_in[10];
  const float* b2rm  = (const float*)d_in[11];
  const float* b2rv  = (const float*)d_in[12];
  const float* b3w   = (const float*)d_in[13];
  const float* b3b   = (const float*)d_in[14];
  const float* b3rm  = (const float*)d_in[15];
  const float* b3rv  = (const float*)d_in[16];
  float* outp = (float*)d_out;

  // workspace carve: w1bf (128 KiB) | w3bf (128 KiB) | folds (9 KiB)
  unsigned short* w1bf = (unsigned short*)d_ws;
  unsigned short* w3bf = (unsigned short*)((char*)d_ws + 131072);
  float*          folds = (float*)((char*)d_ws + 262144);

  hipLaunchKernelGGL(prep_kernel, dim3(256), dim3(256), 0, stream,
                     w1, w2, w3,
                     b1w, b1b, b1rm, b1rv, b2w, b2b, b2rm, b2rv, b3w, b3b, b3rm, b3rv,
                     w1bf, w3bf, folds);

  hipLaunchKernelGGL(fused_main, dim3(NBLK, BATCH, 1), dim3(256, 1, 1), 0, stream,
                     xg, maskg, w1bf, w3bf,
                     folds, folds + 256,          // a1, b1
                     folds + 768,                 // b2 (a2 folded into taps)
                     folds + 1024, folds + 1280,  // a3, b3
                     folds + 1536,                // a2*w2 taps [3][256]
                     outp);
}